// Round 3
// baseline (542.581 us; speedup 1.0000x reference)
//
#include <hip/hip_runtime.h>
#include <math.h>

// Problem constants: B=2, D_e=128, D_o=256, T=16, H=W=64, H_ref=W_ref=32, s=2, k=32
// n_blocks = T*H_ref*W_ref = 16384 per batch; HW_ref = 1024 query blocks per batch.

// ---------------- workspace layout (bytes) ----------------
// [0, 134217728)      : m_out_b [2][16384][4][256] f32 (written by blockify AFTER topk done)
//   -- transient (dead before m_out_b is written, stream-ordered):
//   [0, 4194304)        : cand [2][1024][256] u64 candidate keys
//   [4194304, 5242880)  : Mx [2][128][1024] f32 chunk maxima (chunk-major for coalesced write)
//   [5242880, 5251072)  : t_u [2048] u32 per-column thresholds (mono space)
//   [5251072, 5259264)  : cnt [2048] i32 per-column candidate counts
// [134217728, +64MB)  : m_in_b [2][16384][4][128] f32
// [201326592, +4MB)   : q_b [2][1024][4][128] f32
// [205520896, +256KB) : idx_sorted [2][1024][32] int32

__device__ inline unsigned mono_u32(float f) {
    unsigned b = __float_as_uint(f);
    return (b & 0x80000000u) ? ~b : (b | 0x80000000u);
}

// ---------------- kernel A1: per-(column, 128-row chunk) maxima ----------------
// Full-row streaming: thread owns 4 adjacent columns (float4); wave covers 1KB
// contiguous per row; 128 sequential rows per wg. Grid 256 = 1 wg/CU, each wg
// streams a disjoint 512KB — pure sequential HBM reads.
__global__ __launch_bounds__(256) void qk_chunk_max(const float* __restrict__ qk,
                                                    float* __restrict__ Mx) {
    int wg = blockIdx.x;                 // b*128 + chunk
    int chunk = wg & 127;
    int b = wg >> 7;
    int tid = threadIdx.x;
    const float4* p = (const float4*)(qk + ((size_t)b * 16384 + (size_t)chunk * 128) * 1024) + tid;
    float4 m4;
    m4.x = m4.y = m4.z = m4.w = -__builtin_inff();
#pragma unroll
    for (int rb = 0; rb < 16; ++rb) {
        float4 v[8];
#pragma unroll
        for (int u = 0; u < 8; ++u)
            v[u] = p[(size_t)(rb * 8 + u) * 256];
#pragma unroll
        for (int u = 0; u < 8; ++u) {
            m4.x = fmaxf(m4.x, v[u].x); m4.y = fmaxf(m4.y, v[u].y);
            m4.z = fmaxf(m4.z, v[u].z); m4.w = fmaxf(m4.w, v[u].w);
        }
    }
    ((float4*)Mx)[(size_t)wg * 256 + tid] = m4;   // Mx[b][chunk][col], coalesced
}

// ---------------- kernel A2: conservative per-column threshold ----------------
// t = 32nd-largest of the 128 chunk maxima (distinct u64 keys). >=32 chunks have
// max >= t  =>  >=32 elements >= t  =>  t <= true 32nd-largest element. Zeroes cnt.
__global__ __launch_bounds__(256) void qk_thresh(const float* __restrict__ Mx,
                                                 unsigned* __restrict__ t_u,
                                                 int* __restrict__ cnt) {
    int g = blockIdx.x * 256 + threadIdx.x;
    if (g < 2048) cnt[g] = 0;
    int colg = blockIdx.x * 4 + (threadIdx.x >> 6);   // grid 512 -> colg 0..2047
    int lane = threadIdx.x & 63;
    int b = colg >> 10, col = colg & 1023;
    const float* base = Mx + (size_t)b * 131072 + col;
    float v0 = base[(size_t)lane * 1024];
    float v1 = base[(size_t)(lane + 64) * 1024];
    unsigned long long k0 = ((unsigned long long)mono_u32(v0) << 32) | (unsigned)lane;
    unsigned long long k1 = ((unsigned long long)mono_u32(v1) << 32) | (unsigned)(lane + 64);
    int r0 = 0, r1 = 0;
#pragma unroll 8
    for (int j = 0; j < 64; ++j) {
        unsigned long long o0 = __shfl(k0, j, 64);
        unsigned long long o1 = __shfl(k1, j, 64);
        r0 += (o0 > k0) ? 1 : 0; r0 += (o1 > k0) ? 1 : 0;
        r1 += (o0 > k1) ? 1 : 0; r1 += (o1 > k1) ? 1 : 0;
    }
    if (r0 == 31) t_u[colg] = (unsigned)(k0 >> 32);
    if (r1 == 31) t_u[colg] = (unsigned)(k1 >> 32);
}

// ---------------- kernel A3: filter pass — append candidates >= t ----------------
// Same full-row streaming layout as A1 (qk should be L3-resident after A1).
__global__ __launch_bounds__(256) void qk_filter(const float* __restrict__ qk,
                                                 const unsigned* __restrict__ t_u,
                                                 int* __restrict__ cnt,
                                                 unsigned long long* __restrict__ cand) {
    int wg = blockIdx.x;                 // b*128 + chunk
    int chunk = wg & 127;
    int b = wg >> 7;
    int tid = threadIdx.x;
    const float4* p = (const float4*)(qk + ((size_t)b * 16384 + (size_t)chunk * 128) * 1024) + tid;
    uint4 tu = ((const uint4*)t_u)[b * 256 + tid];  // thresholds for cols 4tid..4tid+3
    int colg0 = b * 1024 + 4 * tid;
#pragma unroll
    for (int rb = 0; rb < 16; ++rb) {
        float4 v[8];
#pragma unroll
        for (int u = 0; u < 8; ++u)
            v[u] = p[(size_t)(rb * 8 + u) * 256];
#pragma unroll
        for (int u = 0; u < 8; ++u) {
            int row = chunk * 128 + rb * 8 + u;
            unsigned ux = mono_u32(v[u].x), uy = mono_u32(v[u].y);
            unsigned uz = mono_u32(v[u].z), uw = mono_u32(v[u].w);
            if (ux >= tu.x) {
                int pos = atomicAdd(&cnt[colg0 + 0], 1);
                if (pos < 256) cand[(size_t)(colg0 + 0) * 256 + pos] =
                    ((unsigned long long)ux << 32) | (unsigned long long)(16383 - row);
            }
            if (uy >= tu.y) {
                int pos = atomicAdd(&cnt[colg0 + 1], 1);
                if (pos < 256) cand[(size_t)(colg0 + 1) * 256 + pos] =
                    ((unsigned long long)uy << 32) | (unsigned long long)(16383 - row);
            }
            if (uz >= tu.z) {
                int pos = atomicAdd(&cnt[colg0 + 2], 1);
                if (pos < 256) cand[(size_t)(colg0 + 2) * 256 + pos] =
                    ((unsigned long long)uz << 32) | (unsigned long long)(16383 - row);
            }
            if (uw >= tu.w) {
                int pos = atomicAdd(&cnt[colg0 + 3], 1);
                if (pos < 256) cand[(size_t)(colg0 + 3) * 256 + pos] =
                    ((unsigned long long)uw << 32) | (unsigned long long)(16383 - row);
            }
        }
    }
}

// ---------------- kernel B: exact top-32 from candidates ----------------
__global__ __launch_bounds__(256) void topk_select(const unsigned long long* __restrict__ cand,
                                                   const int* __restrict__ cnt,
                                                   const float* __restrict__ qk,
                                                   float* __restrict__ out_idx,
                                                   float* __restrict__ out_val,
                                                   int* __restrict__ idx_sorted) {
    int bid = blockIdx.x;                // colg = b*1024 + q
    int tid = threadIdx.x;
    __shared__ unsigned long long sc[256];
    __shared__ unsigned long long selk[32];

    int C = cnt[bid];
    if (C <= 256) {
        if (tid < C) sc[tid] = cand[(size_t)bid * 256 + tid];
        __syncthreads();
        if (tid < C) {
            unsigned long long mine = sc[tid];
            int rank = 0;
            for (int j = 0; j < C; ++j) rank += (sc[j] > mine) ? 1 : 0;
            if (rank < 32) selk[rank] = mine;
        }
        __syncthreads();
    } else {
        // exact fallback: 32 rounds of strictly-descending key extraction
        int b = bid >> 10, q = bid & 1023;
        const float* colp = qk + (size_t)b * 16384 * 1024 + q;
        unsigned long long prev = ~0ull;
#pragma unroll 1
        for (int s = 0; s < 32; ++s) {
            unsigned long long best = 0;
            for (int r = tid; r < 16384; r += 256) {
                unsigned long long k =
                    ((unsigned long long)mono_u32(colp[(size_t)r * 1024]) << 32) |
                    (unsigned long long)(16383 - r);
                if (k < prev && k > best) best = k;
            }
            sc[tid] = best;
            __syncthreads();
            for (int off = 128; off >= 1; off >>= 1) {
                if (tid < off && sc[tid + off] > sc[tid]) sc[tid] = sc[tid + off];
                __syncthreads();
            }
            if (tid == 0) selk[s] = sc[0];
            __syncthreads();
            prev = selk[s];
        }
    }

    if (tid < 8) {
        unsigned long long k = selk[tid];
        unsigned uv = (unsigned)(k >> 32);
        unsigned bits = (uv & 0x80000000u) ? (uv ^ 0x80000000u) : ~uv;
        out_val[(size_t)bid * 8 + tid] = __uint_as_float(bits);
        int gi = 16383 - (int)(k & 0xFFFFFFFFull);
        out_idx[(size_t)bid * 8 + tid] = (float)gi;
    }
    if (tid < 32) {                      // 32 distinct indices -> ascending by rank
        int mine = 16383 - (int)(selk[tid] & 0xFFFFFFFFull);
        int rank = 0;
#pragma unroll
        for (int j = 0; j < 32; ++j) {
            int oj = 16383 - (int)(selk[j] & 0xFFFFFFFFull);
            rank += (oj < mine) ? 1 : 0;
        }
        idx_sorted[(size_t)bid * 32 + rank] = mine;
    }
}

// ---------------- kernel 3: blockify v2 [B,D,T,64,64] -> [B, T*1024, 4, D] ----------------
// wg = (b, t, hb, ch-half). Reads: per channel the row-PAIR (2hb,2hb+1) = 512B
// contiguous. Writes: [n][p][c] float4 along c = 512B segments. XOR-swizzled
// exact-64KB LDS tile (~4-way read conflicts, not on the critical path).
template <int D, int T>
__global__ __launch_bounds__(256) void blockify2(const float* __restrict__ in,
                                                 float* __restrict__ out) {
    constexpr int NH = D / 128;
    __shared__ float tile[128][128];     // 64KB exact; tile[c][pos ^ swz(c)]
    int wg = blockIdx.x;
    int h  = wg % NH;
    int hb = (wg / NH) % 32;
    int t  = (wg / (NH * 32)) % T;
    int b  = wg / (NH * 32 * T);
    int tid = threadIdx.x;

    // phase 1: stage 128 channels x 128 floats (row-pair), 16 staged float4 loads
    {
        int m   = tid & 31;              // float4 slot within row-pair
        int cl0 = tid >> 5;              // 0..7
        float4 v[16];
#pragma unroll
        for (int pass = 0; pass < 16; ++pass) {
            int c = pass * 8 + cl0;
            const float* src = in +
                ((size_t)(b * D + h * 128 + c) * T + t) * 4096 + (size_t)hb * 128;
            v[pass] = *(const float4*)(src + 4 * m);
        }
#pragma unroll
        for (int pass = 0; pass < 16; ++pass) {
            int c = pass * 8 + cl0;
            int sw = ((c >> 2) & 31) << 2;
            *(float4*)&tile[c][(4 * m) ^ sw] = v[pass];
        }
    }
    __syncthreads();

    // phase 2: write (wb, p, c) -> out[n][p][h*128 + c], float4 along c
    {
        size_t slab = (((size_t)b * T + t) * 1024 + (size_t)hb * 32) * (4 * D) +
                      (size_t)h * 128;
#pragma unroll
        for (int it = 0; it < 16; ++it) {
            int flat = it * 1024 + tid * 4;  // over (wb:32, p:4, c:128)
            int cl = flat & 127;             // multiple of 4
            int pp = (flat >> 7) & 3;
            int wb = flat >> 9;
            int pos = ((pp >> 1) << 6) + 2 * wb + (pp & 1);
            int sw = ((cl >> 2) & 31) << 2;  // same for cl..cl+3
            float4 o;
            o.x = tile[cl + 0][pos ^ sw];
            o.y = tile[cl + 1][pos ^ sw];
            o.z = tile[cl + 2][pos ^ sw];
            o.w = tile[cl + 3][pos ^ sw];
            *(float4*)(out + slab + (size_t)wb * 4 * D + (size_t)pp * D + cl) = o;
        }
    }
}

// ---------------- kernel 4: gathered block attention ----------------
__global__ __launch_bounds__(256) void attn_kernel(const float* __restrict__ m_in_b,
                                                   const float* __restrict__ m_out_b,
                                                   const float* __restrict__ q_b,
                                                   const int* __restrict__ idx_sorted,
                                                   float* __restrict__ out) {
    int bid = blockIdx.x;
    int b = bid >> 10, qblk = bid & 1023;
    int hb = qblk >> 5, wb = qblk & 31;
    int tid = threadIdx.x;
    int w = tid >> 6, lane = tid & 63;

    __shared__ float K[64][129];
    __shared__ float Q[4][128];
    __shared__ float P[4][128];
    __shared__ int   blks[32];

    if (tid < 32) blks[tid] = idx_sorted[(size_t)bid * 32 + tid];
    {
        const float* qsrc = q_b + (size_t)bid * 512;
        ((float*)Q)[tid]       = qsrc[tid];
        ((float*)Q)[tid + 256] = qsrc[tid + 256];
    }
    __syncthreads();

    const float scale = 0.08838834764831845f;
    float s01[2];
#pragma unroll 1
    for (int half = 0; half < 2; ++half) {
        if (half) __syncthreads();
#pragma unroll 4
        for (int ki = 0; ki < 16; ++ki) {
            int blk = blks[half * 16 + ki];
            const float* src = m_in_b + ((size_t)b * 16384 + blk) * 512;
            int p0 = tid >> 7, c0 = tid & 127;
            K[ki * 4 + p0][c0]     = src[tid];
            K[ki * 4 + p0 + 2][c0] = src[tid + 256];
        }
        __syncthreads();
        float acc = 0.f;
#pragma unroll 4
        for (int c = 0; c < 128; ++c) acc += K[lane][c] * Q[w][c];
        s01[half] = acc * scale;
    }

    float m = fmaxf(s01[0], s01[1]);
#pragma unroll
    for (int off = 32; off >= 1; off >>= 1) m = fmaxf(m, __shfl_xor(m, off, 64));
    float e0 = expf(s01[0] - m), e1 = expf(s01[1] - m);
    float sum = e0 + e1;
#pragma unroll
    for (int off = 32; off >= 1; off >>= 1) sum += __shfl_xor(sum, off, 64);
    float inv = 1.0f / sum;
    P[w][lane]      = e0 * inv;
    P[w][lane + 64] = e1 * inv;
    __syncthreads();

    float a0 = 0.f, a1 = 0.f, a2 = 0.f, a3 = 0.f;
    int d = tid;
#pragma unroll 1
    for (int ki = 0; ki < 32; ++ki) {
        const float* vsrc = m_out_b + ((size_t)b * 16384 + blks[ki]) * 1024;
#pragma unroll
        for (int p = 0; p < 4; ++p) {
            float vv = vsrc[p * 256 + d];
            int n = ki * 4 + p;
            a0 += P[0][n] * vv; a1 += P[1][n] * vv;
            a2 += P[2][n] * vv; a3 += P[3][n] * vv;
        }
    }
    size_t base = (((size_t)b * 256 + d) * 64 + hb * 2) * 64 + wb * 2;
    out[base]      = a0;
    out[base + 1]  = a1;
    out[base + 64] = a2;
    out[base + 65] = a3;
}

extern "C" void kernel_launch(void* const* d_in, const int* in_sizes, int n_in,
                              void* d_out, int out_size, void* d_ws, size_t ws_size,
                              hipStream_t stream) {
    const float* m_in  = (const float*)d_in[0];
    const float* m_out = (const float*)d_in[1];
    const float* q_in  = (const float*)d_in[2];
    const float* qk    = (const float*)d_in[3];

    char* ws = (char*)d_ws;
    float* m_out_b = (float*)(ws);                 // written after topk chain completes
    float* m_in_b  = (float*)(ws + 134217728);
    float* q_b     = (float*)(ws + 201326592);
    int*   idxs    = (int*)  (ws + 205520896);

    // transient top-k scratch inside the (not-yet-written) m_out_b region
    unsigned long long* cand = (unsigned long long*)(ws);        // 4MB
    float*    Mx  = (float*)   (ws + 4194304);                   // 1MB
    unsigned* t_u = (unsigned*)(ws + 5242880);                   // 8KB
    int*      cnt = (int*)     (ws + 5251072);                   // 8KB

    float* out     = (float*)d_out;
    float* out_mem = out;
    float* out_idx = out + 2097152;
    float* out_val = out + 2113536;

    qk_chunk_max<<<256, 256, 0, stream>>>(qk, Mx);
    qk_thresh   <<<512, 256, 0, stream>>>(Mx, t_u, cnt);
    qk_filter   <<<256, 256, 0, stream>>>(qk, t_u, cnt, cand);
    topk_select <<<2048, 256, 0, stream>>>(cand, cnt, qk, out_idx, out_val, idxs);

    blockify2<128, 16><<<1024, 256, 0, stream>>>(m_in, m_in_b);
    blockify2<128, 1><<<64, 256, 0, stream>>>(q_in, q_b);
    blockify2<256, 16><<<2048, 256, 0, stream>>>(m_out, m_out_b);
    attn_kernel<<<2048, 256, 0, stream>>>(m_in_b, m_out_b, q_b, idxs, out_mem);
}

// Round 4
// 472.218 us; speedup vs baseline: 1.1490x; 1.1490x over previous
//
#include <hip/hip_runtime.h>
#include <math.h>

// Problem constants: B=2, D_e=128, D_o=256, T=16, H=W=64, H_ref=W_ref=32, s=2, k=32
// n_blocks = T*H_ref*W_ref = 16384 per batch; HW_ref = 1024 query blocks per batch.

// ---------------- workspace layout (bytes) ----------------
// [0, 134217728)      : m_out_b [2][16384][4][256] f32 (written by blockify AFTER topk done)
//   -- transient (dead before m_out_b is written, stream-ordered):
//   [0, 4194304)        : cand [2][1024][256] u64 candidate keys
//   [4194304, 8388608)  : Mx [2][512][1024] f32 chunk maxima (chunk-major, coalesced write)
//   [8388608, 8396800)  : t_u [2048] u32 per-column thresholds (mono space)
//   [8396800, 8404992)  : cnt [2048] i32 per-column candidate counts
// [134217728, +64MB)  : m_in_b [2][16384][4][128] f32
// [201326592, +4MB)   : q_b [2][1024][4][128] f32
// [205520896, +256KB) : idx_sorted [2][1024][32] int32

__device__ inline unsigned mono_u32(float f) {
    unsigned b = __float_as_uint(f);
    return (b & 0x80000000u) ? ~b : (b | 0x80000000u);
}

// ---------------- kernel A1: per-(column, 32-row chunk) maxima ----------------
// Grid 1024 (4 wg/CU, 16 waves/CU -> TLP latency hiding). Thread owns 4 adjacent
// columns (float4); the wg covers a full 4KB row; 32 sequential rows per wg.
__global__ __launch_bounds__(256) void qk_chunk_max(const float* __restrict__ qk,
                                                    float* __restrict__ Mx) {
    int wg = blockIdx.x;                 // b*512 + chunk
    int chunk = wg & 511;
    int b = wg >> 9;
    int tid = threadIdx.x;
    const float4* p = (const float4*)(qk + ((size_t)b * 16384 + (size_t)chunk * 32) * 1024) + tid;
    float4 m4;
    m4.x = m4.y = m4.z = m4.w = -__builtin_inff();
#pragma unroll
    for (int rb = 0; rb < 4; ++rb) {
        float4 v[8];
#pragma unroll
        for (int u = 0; u < 8; ++u)
            v[u] = p[(size_t)(rb * 8 + u) * 256];
#pragma unroll
        for (int u = 0; u < 8; ++u) {
            m4.x = fmaxf(m4.x, v[u].x); m4.y = fmaxf(m4.y, v[u].y);
            m4.z = fmaxf(m4.z, v[u].z); m4.w = fmaxf(m4.w, v[u].w);
        }
    }
    ((float4*)Mx)[(size_t)wg * 256 + tid] = m4;   // Mx[b][chunk][col], coalesced
}

// ---------------- kernel A2: conservative per-column threshold ----------------
// One wg per column. Two-pass 8-bit histogram over the 512 chunk maxima -> 16-bit
// floor t_u <= 32nd-largest chunk max <= 32nd-largest element (superset guarantee).
__global__ __launch_bounds__(256) void qk_thresh(const float* __restrict__ Mx,
                                                 unsigned* __restrict__ t_u,
                                                 int* __restrict__ cnt) {
    int colg = blockIdx.x;               // 0..2047
    int tid = threadIdx.x;
    int b = colg >> 10, col = colg & 1023;
    const float* base = Mx + (size_t)b * 524288 + col;
    unsigned u0 = mono_u32(base[(size_t)tid * 1024]);
    unsigned u1 = mono_u32(base[(size_t)(tid + 256) * 1024]);

    __shared__ int hist1[256];
    __shared__ int hist2[256];
    __shared__ int s_b1, s_above1;
    __shared__ unsigned s_tu;
    hist1[tid] = 0; hist2[tid] = 0;
    __syncthreads();

    atomicAdd(&hist1[u0 >> 24], 1);
    atomicAdd(&hist1[u1 >> 24], 1);
    __syncthreads();

    if (tid < 64) {
        int base4 = 252 - 4 * tid;       // lane 0 covers top bins
        int h0 = hist1[base4], h1 = hist1[base4 + 1], h2 = hist1[base4 + 2], h3 = hist1[base4 + 3];
        int gs = h0 + h1 + h2 + h3;
        int pre = gs;
#pragma unroll
        for (int off = 1; off < 64; off <<= 1) {
            int o = __shfl_up(pre, off, 64);
            if (tid >= off) pre += o;
        }
        int excl = pre - gs;
        if (excl < 32 && pre >= 32) {    // crossing group (exactly one lane)
            int c = excl, bb, ab;
            c += h3; if (c >= 32) { bb = base4 + 3; ab = c - h3; }
            else { c += h2; if (c >= 32) { bb = base4 + 2; ab = c - h2; }
            else { c += h1; if (c >= 32) { bb = base4 + 1; ab = c - h1; }
            else { c += h0;   bb = base4;     ab = c - h0; } } }
            s_b1 = bb; s_above1 = ab;
        }
    }
    __syncthreads();
    int b1 = s_b1;
    if ((int)(u0 >> 24) == b1) atomicAdd(&hist2[(u0 >> 16) & 0xFF], 1);
    if ((int)(u1 >> 24) == b1) atomicAdd(&hist2[(u1 >> 16) & 0xFF], 1);
    __syncthreads();

    if (tid < 64) {
        int A = s_above1;
        int base4 = 252 - 4 * tid;
        int h0 = hist2[base4], h1 = hist2[base4 + 1], h2 = hist2[base4 + 2], h3 = hist2[base4 + 3];
        int gs = h0 + h1 + h2 + h3;
        int pre = gs;
#pragma unroll
        for (int off = 1; off < 64; off <<= 1) {
            int o = __shfl_up(pre, off, 64);
            if (tid >= off) pre += o;
        }
        int excl = pre - gs;
        if (A + excl < 32 && A + pre >= 32) {
            int c = A + excl, bb;
            c += h3; if (c >= 32) bb = base4 + 3;
            else { c += h2; if (c >= 32) bb = base4 + 2;
            else { c += h1; if (c >= 32) bb = base4 + 1;
            else { bb = base4; } } }
            s_tu = (((unsigned)b1 << 8) | (unsigned)bb) << 16;
        }
    }
    __syncthreads();
    if (tid == 0) { t_u[colg] = s_tu; cnt[colg] = 0; }
}

// ---------------- kernel A3: filter pass — branch-free masks, epilogue append ----------------
// Same streaming layout as A1. Hot loop: loads + compare/or only (no atomics/stores,
// so the compiler can pipeline the loads). Survivors (~0.3/thread) appended in the
// epilogue, re-reading values from L2 (wg's 128KB chunk is resident).
__global__ __launch_bounds__(256) void qk_filter(const float* __restrict__ qk,
                                                 const unsigned* __restrict__ t_u,
                                                 int* __restrict__ cnt,
                                                 unsigned long long* __restrict__ cand) {
    int wg = blockIdx.x;                 // b*512 + chunk
    int chunk = wg & 511;
    int b = wg >> 9;
    int tid = threadIdx.x;
    const float4* p = (const float4*)(qk + ((size_t)b * 16384 + (size_t)chunk * 32) * 1024) + tid;
    uint4 tu = ((const uint4*)t_u)[b * 256 + tid];  // thresholds for cols 4tid..4tid+3

    unsigned mxm = 0, mym = 0, mzm = 0, mwm = 0;    // bit r: row (chunk*32+r) survives
#pragma unroll
    for (int rb = 0; rb < 4; ++rb) {
        float4 v[8];
#pragma unroll
        for (int u = 0; u < 8; ++u)
            v[u] = p[(size_t)(rb * 8 + u) * 256];
#pragma unroll
        for (int u = 0; u < 8; ++u) {
            int r = rb * 8 + u;
            mxm |= (mono_u32(v[u].x) >= tu.x ? 1u : 0u) << r;
            mym |= (mono_u32(v[u].y) >= tu.y ? 1u : 0u) << r;
            mzm |= (mono_u32(v[u].z) >= tu.z ? 1u : 0u) << r;
            mwm |= (mono_u32(v[u].w) >= tu.w ? 1u : 0u) << r;
        }
    }

    int row0 = chunk * 32;
    int colg0 = b * 1024 + 4 * tid;
    const float* q0 = qk + ((size_t)b * 16384 + row0) * 1024 + 4 * tid;
    unsigned msk[4] = {mxm, mym, mzm, mwm};
#pragma unroll
    for (int j = 0; j < 4; ++j) {
        unsigned m = msk[j];
        while (m) {
            int r = __ffs(m) - 1;
            m &= m - 1;
            unsigned uu = mono_u32(q0[(size_t)r * 1024 + j]);
            int pos = atomicAdd(&cnt[colg0 + j], 1);
            if (pos < 256)
                cand[(size_t)(colg0 + j) * 256 + pos] =
                    ((unsigned long long)uu << 32) |
                    (unsigned long long)(16383 - (row0 + r));
        }
    }
}

// ---------------- kernel B: exact top-32 from candidates ----------------
__global__ __launch_bounds__(256) void topk_select(const unsigned long long* __restrict__ cand,
                                                   const int* __restrict__ cnt,
                                                   const float* __restrict__ qk,
                                                   float* __restrict__ out_idx,
                                                   float* __restrict__ out_val,
                                                   int* __restrict__ idx_sorted) {
    int bid = blockIdx.x;                // colg = b*1024 + q
    int tid = threadIdx.x;
    __shared__ unsigned long long sc[256];
    __shared__ unsigned long long selk[32];

    int C = cnt[bid];
    if (C <= 256) {
        if (tid < C) sc[tid] = cand[(size_t)bid * 256 + tid];
        __syncthreads();
        if (tid < C) {
            unsigned long long mine = sc[tid];
            int rank = 0;
            for (int j = 0; j < C; ++j) rank += (sc[j] > mine) ? 1 : 0;
            if (rank < 32) selk[rank] = mine;
        }
        __syncthreads();
    } else {
        // exact fallback: 32 rounds of strictly-descending key extraction
        int b = bid >> 10, q = bid & 1023;
        const float* colp = qk + (size_t)b * 16384 * 1024 + q;
        unsigned long long prev = ~0ull;
#pragma unroll 1
        for (int s = 0; s < 32; ++s) {
            unsigned long long best = 0;
            for (int r = tid; r < 16384; r += 256) {
                unsigned long long k =
                    ((unsigned long long)mono_u32(colp[(size_t)r * 1024]) << 32) |
                    (unsigned long long)(16383 - r);
                if (k < prev && k > best) best = k;
            }
            sc[tid] = best;
            __syncthreads();
            for (int off = 128; off >= 1; off >>= 1) {
                if (tid < off && sc[tid + off] > sc[tid]) sc[tid] = sc[tid + off];
                __syncthreads();
            }
            if (tid == 0) selk[s] = sc[0];
            __syncthreads();
            prev = selk[s];
        }
    }

    if (tid < 8) {
        unsigned long long k = selk[tid];
        unsigned uv = (unsigned)(k >> 32);
        unsigned bits = (uv & 0x80000000u) ? (uv ^ 0x80000000u) : ~uv;
        out_val[(size_t)bid * 8 + tid] = __uint_as_float(bits);
        int gi = 16383 - (int)(k & 0xFFFFFFFFull);
        out_idx[(size_t)bid * 8 + tid] = (float)gi;
    }
    if (tid < 32) {                      // 32 distinct indices -> ascending by rank
        int mine = 16383 - (int)(selk[tid] & 0xFFFFFFFFull);
        int rank = 0;
#pragma unroll
        for (int j = 0; j < 32; ++j) {
            int oj = 16383 - (int)(selk[j] & 0xFFFFFFFFull);
            rank += (oj < mine) ? 1 : 0;
        }
        idx_sorted[(size_t)bid * 32 + rank] = mine;
    }
}

// ---------------- kernel 3: blockify v2 [B,D,T,64,64] -> [B, T*1024, 4, D] ----------------
// wg = (b, t, hb, ch-half). Reads: per channel the row-PAIR (2hb,2hb+1) = 512B
// contiguous. Writes: [n][p][c] float4 along c = 512B segments. XOR-swizzled
// exact-64KB LDS tile (~4-way read conflicts, not on the critical path).
template <int D, int T>
__global__ __launch_bounds__(256) void blockify2(const float* __restrict__ in,
                                                 float* __restrict__ out) {
    constexpr int NH = D / 128;
    __shared__ float tile[128][128];     // 64KB exact; tile[c][pos ^ swz(c)]
    int wg = blockIdx.x;
    int h  = wg % NH;
    int hb = (wg / NH) % 32;
    int t  = (wg / (NH * 32)) % T;
    int b  = wg / (NH * 32 * T);
    int tid = threadIdx.x;

    // phase 1: stage 128 channels x 128 floats (row-pair), 16 staged float4 loads
    {
        int m   = tid & 31;              // float4 slot within row-pair
        int cl0 = tid >> 5;              // 0..7
        float4 v[16];
#pragma unroll
        for (int pass = 0; pass < 16; ++pass) {
            int c = pass * 8 + cl0;
            const float* src = in +
                ((size_t)(b * D + h * 128 + c) * T + t) * 4096 + (size_t)hb * 128;
            v[pass] = *(const float4*)(src + 4 * m);
        }
#pragma unroll
        for (int pass = 0; pass < 16; ++pass) {
            int c = pass * 8 + cl0;
            int sw = ((c >> 2) & 31) << 2;
            *(float4*)&tile[c][(4 * m) ^ sw] = v[pass];
        }
    }
    __syncthreads();

    // phase 2: write (wb, p, c) -> out[n][p][h*128 + c], float4 along c
    {
        size_t slab = (((size_t)b * T + t) * 1024 + (size_t)hb * 32) * (4 * D) +
                      (size_t)h * 128;
#pragma unroll
        for (int it = 0; it < 16; ++it) {
            int flat = it * 1024 + tid * 4;  // over (wb:32, p:4, c:128)
            int cl = flat & 127;             // multiple of 4
            int pp = (flat >> 7) & 3;
            int wb = flat >> 9;
            int pos = ((pp >> 1) << 6) + 2 * wb + (pp & 1);
            int sw = ((cl >> 2) & 31) << 2;  // same for cl..cl+3
            float4 o;
            o.x = tile[cl + 0][pos ^ sw];
            o.y = tile[cl + 1][pos ^ sw];
            o.z = tile[cl + 2][pos ^ sw];
            o.w = tile[cl + 3][pos ^ sw];
            *(float4*)(out + slab + (size_t)wb * 4 * D + (size_t)pp * D + cl) = o;
        }
    }
}

// ---------------- kernel 4: gathered block attention ----------------
__global__ __launch_bounds__(256) void attn_kernel(const float* __restrict__ m_in_b,
                                                   const float* __restrict__ m_out_b,
                                                   const float* __restrict__ q_b,
                                                   const int* __restrict__ idx_sorted,
                                                   float* __restrict__ out) {
    int bid = blockIdx.x;
    int b = bid >> 10, qblk = bid & 1023;
    int hb = qblk >> 5, wb = qblk & 31;
    int tid = threadIdx.x;
    int w = tid >> 6, lane = tid & 63;

    __shared__ float K[64][129];
    __shared__ float Q[4][128];
    __shared__ float P[4][128];
    __shared__ int   blks[32];

    if (tid < 32) blks[tid] = idx_sorted[(size_t)bid * 32 + tid];
    {
        const float* qsrc = q_b + (size_t)bid * 512;
        ((float*)Q)[tid]       = qsrc[tid];
        ((float*)Q)[tid + 256] = qsrc[tid + 256];
    }
    __syncthreads();

    const float scale = 0.08838834764831845f;
    float s01[2];
#pragma unroll 1
    for (int half = 0; half < 2; ++half) {
        if (half) __syncthreads();
#pragma unroll 4
        for (int ki = 0; ki < 16; ++ki) {
            int blk = blks[half * 16 + ki];
            const float* src = m_in_b + ((size_t)b * 16384 + blk) * 512;
            int p0 = tid >> 7, c0 = tid & 127;
            K[ki * 4 + p0][c0]     = src[tid];
            K[ki * 4 + p0 + 2][c0] = src[tid + 256];
        }
        __syncthreads();
        float acc = 0.f;
#pragma unroll 4
        for (int c = 0; c < 128; ++c) acc += K[lane][c] * Q[w][c];
        s01[half] = acc * scale;
    }

    float m = fmaxf(s01[0], s01[1]);
#pragma unroll
    for (int off = 32; off >= 1; off >>= 1) m = fmaxf(m, __shfl_xor(m, off, 64));
    float e0 = expf(s01[0] - m), e1 = expf(s01[1] - m);
    float sum = e0 + e1;
#pragma unroll
    for (int off = 32; off >= 1; off >>= 1) sum += __shfl_xor(sum, off, 64);
    float inv = 1.0f / sum;
    P[w][lane]      = e0 * inv;
    P[w][lane + 64] = e1 * inv;
    __syncthreads();

    float a0 = 0.f, a1 = 0.f, a2 = 0.f, a3 = 0.f;
    int d = tid;
#pragma unroll 1
    for (int ki = 0; ki < 32; ++ki) {
        const float* vsrc = m_out_b + ((size_t)b * 16384 + blks[ki]) * 1024;
#pragma unroll
        for (int p = 0; p < 4; ++p) {
            float vv = vsrc[p * 256 + d];
            int n = ki * 4 + p;
            a0 += P[0][n] * vv; a1 += P[1][n] * vv;
            a2 += P[2][n] * vv; a3 += P[3][n] * vv;
        }
    }
    size_t base = (((size_t)b * 256 + d) * 64 + hb * 2) * 64 + wb * 2;
    out[base]      = a0;
    out[base + 1]  = a1;
    out[base + 64] = a2;
    out[base + 65] = a3;
}

extern "C" void kernel_launch(void* const* d_in, const int* in_sizes, int n_in,
                              void* d_out, int out_size, void* d_ws, size_t ws_size,
                              hipStream_t stream) {
    const float* m_in  = (const float*)d_in[0];
    const float* m_out = (const float*)d_in[1];
    const float* q_in  = (const float*)d_in[2];
    const float* qk    = (const float*)d_in[3];

    char* ws = (char*)d_ws;
    float* m_out_b = (float*)(ws);                 // written after topk chain completes
    float* m_in_b  = (float*)(ws + 134217728);
    float* q_b     = (float*)(ws + 201326592);
    int*   idxs    = (int*)  (ws + 205520896);

    // transient top-k scratch inside the (not-yet-written) m_out_b region
    unsigned long long* cand = (unsigned long long*)(ws);        // 4MB
    float*    Mx  = (float*)   (ws + 4194304);                   // 4MB
    unsigned* t_u = (unsigned*)(ws + 8388608);                   // 8KB
    int*      cnt = (int*)     (ws + 8396800);                   // 8KB

    float* out     = (float*)d_out;
    float* out_mem = out;
    float* out_idx = out + 2097152;
    float* out_val = out + 2113536;

    qk_chunk_max<<<1024, 256, 0, stream>>>(qk, Mx);
    qk_thresh   <<<2048, 256, 0, stream>>>(Mx, t_u, cnt);
    qk_filter   <<<1024, 256, 0, stream>>>(qk, t_u, cnt, cand);
    topk_select <<<2048, 256, 0, stream>>>(cand, cnt, qk, out_idx, out_val, idxs);

    blockify2<128, 16><<<1024, 256, 0, stream>>>(m_in, m_in_b);
    blockify2<128, 1><<<64, 256, 0, stream>>>(q_in, q_b);
    blockify2<256, 16><<<2048, 256, 0, stream>>>(m_out, m_out_b);
    attn_kernel<<<2048, 256, 0, stream>>>(m_in_b, m_out_b, q_b, idxs, out_mem);
}

// Round 5
// 468.687 us; speedup vs baseline: 1.1577x; 1.0075x over previous
//
#include <hip/hip_runtime.h>
#include <math.h>

// Problem constants: B=2, D_e=128, D_o=256, T=16, H=W=64, H_ref=W_ref=32, s=2, k=32
// n_blocks = T*H_ref*W_ref = 16384 per batch; HW_ref = 1024 query blocks per batch.

// ---------------- workspace layout (bytes) ----------------
// [0, 134217728)      : m_out_b [2][16384][4][256] f32 (written by blockify AFTER topk done)
//   -- transient (dead before m_out_b is written, stream-ordered):
//   [0, 4194304)        : cand [2][1024][256] u64 candidate keys
//   [4194304, 8388608)  : Mx [2][512][1024] f32 chunk maxima (chunk-major, coalesced write)
//   [8388608, 8396800)  : t_u [2048] u32 per-column thresholds (mono space)
//   [8396800, 8404992)  : cnt [2048] i32 per-column candidate counts
// [134217728, +64MB)  : m_in_b [2][16384][4][128] f32
// [201326592, +4MB)   : q_b [2][1024][4][128] f32
// [205520896, +256KB) : idx_sorted [2][1024][32] int32

__device__ inline unsigned mono_u32(float f) {
    unsigned b = __float_as_uint(f);
    return (b & 0x80000000u) ? ~b : (b | 0x80000000u);
}

// ---------------- kernel A1: per-(column, 32-row chunk) maxima ----------------
// Grid 1024 (4 wg/CU, 16 waves/CU -> TLP latency hiding). Thread owns 4 adjacent
// columns (float4); the wg covers a full 4KB row; 32 sequential rows per wg.
__global__ __launch_bounds__(256) void qk_chunk_max(const float* __restrict__ qk,
                                                    float* __restrict__ Mx) {
    int wg = blockIdx.x;                 // b*512 + chunk
    int chunk = wg & 511;
    int b = wg >> 9;
    int tid = threadIdx.x;
    const float4* p = (const float4*)(qk + ((size_t)b * 16384 + (size_t)chunk * 32) * 1024) + tid;
    float4 m4;
    m4.x = m4.y = m4.z = m4.w = -__builtin_inff();
#pragma unroll
    for (int rb = 0; rb < 4; ++rb) {
        float4 v[8];
#pragma unroll
        for (int u = 0; u < 8; ++u)
            v[u] = p[(size_t)(rb * 8 + u) * 256];
#pragma unroll
        for (int u = 0; u < 8; ++u) {
            m4.x = fmaxf(m4.x, v[u].x); m4.y = fmaxf(m4.y, v[u].y);
            m4.z = fmaxf(m4.z, v[u].z); m4.w = fmaxf(m4.w, v[u].w);
        }
    }
    ((float4*)Mx)[(size_t)wg * 256 + tid] = m4;   // Mx[b][chunk][col], coalesced
}

// ---------------- kernel A2: conservative per-column threshold ----------------
// One wg per column. Two-pass 8-bit histogram over the 512 chunk maxima -> 16-bit
// floor t_u <= 32nd-largest chunk max <= 32nd-largest element (superset guarantee).
__global__ __launch_bounds__(256) void qk_thresh(const float* __restrict__ Mx,
                                                 unsigned* __restrict__ t_u,
                                                 int* __restrict__ cnt) {
    int colg = blockIdx.x;               // 0..2047
    int tid = threadIdx.x;
    int b = colg >> 10, col = colg & 1023;
    const float* base = Mx + (size_t)b * 524288 + col;
    unsigned u0 = mono_u32(base[(size_t)tid * 1024]);
    unsigned u1 = mono_u32(base[(size_t)(tid + 256) * 1024]);

    __shared__ int hist1[256];
    __shared__ int hist2[256];
    __shared__ int s_b1, s_above1;
    __shared__ unsigned s_tu;
    hist1[tid] = 0; hist2[tid] = 0;
    __syncthreads();

    atomicAdd(&hist1[u0 >> 24], 1);
    atomicAdd(&hist1[u1 >> 24], 1);
    __syncthreads();

    if (tid < 64) {
        int base4 = 252 - 4 * tid;       // lane 0 covers top bins
        int h0 = hist1[base4], h1 = hist1[base4 + 1], h2 = hist1[base4 + 2], h3 = hist1[base4 + 3];
        int gs = h0 + h1 + h2 + h3;
        int pre = gs;
#pragma unroll
        for (int off = 1; off < 64; off <<= 1) {
            int o = __shfl_up(pre, off, 64);
            if (tid >= off) pre += o;
        }
        int excl = pre - gs;
        if (excl < 32 && pre >= 32) {    // crossing group (exactly one lane)
            int c = excl, bb, ab;
            c += h3; if (c >= 32) { bb = base4 + 3; ab = c - h3; }
            else { c += h2; if (c >= 32) { bb = base4 + 2; ab = c - h2; }
            else { c += h1; if (c >= 32) { bb = base4 + 1; ab = c - h1; }
            else { c += h0;   bb = base4;     ab = c - h0; } } }
            s_b1 = bb; s_above1 = ab;
        }
    }
    __syncthreads();
    int b1 = s_b1;
    if ((int)(u0 >> 24) == b1) atomicAdd(&hist2[(u0 >> 16) & 0xFF], 1);
    if ((int)(u1 >> 24) == b1) atomicAdd(&hist2[(u1 >> 16) & 0xFF], 1);
    __syncthreads();

    if (tid < 64) {
        int A = s_above1;
        int base4 = 252 - 4 * tid;
        int h0 = hist2[base4], h1 = hist2[base4 + 1], h2 = hist2[base4 + 2], h3 = hist2[base4 + 3];
        int gs = h0 + h1 + h2 + h3;
        int pre = gs;
#pragma unroll
        for (int off = 1; off < 64; off <<= 1) {
            int o = __shfl_up(pre, off, 64);
            if (tid >= off) pre += o;
        }
        int excl = pre - gs;
        if (A + excl < 32 && A + pre >= 32) {
            int c = A + excl, bb;
            c += h3; if (c >= 32) bb = base4 + 3;
            else { c += h2; if (c >= 32) bb = base4 + 2;
            else { c += h1; if (c >= 32) bb = base4 + 1;
            else { bb = base4; } } }
            s_tu = (((unsigned)b1 << 8) | (unsigned)bb) << 16;
        }
    }
    __syncthreads();
    if (tid == 0) { t_u[colg] = s_tu; cnt[colg] = 0; }
}

// ---------------- kernel A3: filter pass — branch-free masks, epilogue append ----------------
__global__ __launch_bounds__(256) void qk_filter(const float* __restrict__ qk,
                                                 const unsigned* __restrict__ t_u,
                                                 int* __restrict__ cnt,
                                                 unsigned long long* __restrict__ cand) {
    int wg = blockIdx.x;                 // b*512 + chunk
    int chunk = wg & 511;
    int b = wg >> 9;
    int tid = threadIdx.x;
    const float4* p = (const float4*)(qk + ((size_t)b * 16384 + (size_t)chunk * 32) * 1024) + tid;
    uint4 tu = ((const uint4*)t_u)[b * 256 + tid];  // thresholds for cols 4tid..4tid+3

    unsigned mxm = 0, mym = 0, mzm = 0, mwm = 0;    // bit r: row (chunk*32+r) survives
#pragma unroll
    for (int rb = 0; rb < 4; ++rb) {
        float4 v[8];
#pragma unroll
        for (int u = 0; u < 8; ++u)
            v[u] = p[(size_t)(rb * 8 + u) * 256];
#pragma unroll
        for (int u = 0; u < 8; ++u) {
            int r = rb * 8 + u;
            mxm |= (mono_u32(v[u].x) >= tu.x ? 1u : 0u) << r;
            mym |= (mono_u32(v[u].y) >= tu.y ? 1u : 0u) << r;
            mzm |= (mono_u32(v[u].z) >= tu.z ? 1u : 0u) << r;
            mwm |= (mono_u32(v[u].w) >= tu.w ? 1u : 0u) << r;
        }
    }

    int row0 = chunk * 32;
    int colg0 = b * 1024 + 4 * tid;
    const float* q0 = qk + ((size_t)b * 16384 + row0) * 1024 + 4 * tid;
    unsigned msk[4] = {mxm, mym, mzm, mwm};
#pragma unroll
    for (int j = 0; j < 4; ++j) {
        unsigned m = msk[j];
        while (m) {
            int r = __ffs(m) - 1;
            m &= m - 1;
            unsigned uu = mono_u32(q0[(size_t)r * 1024 + j]);
            int pos = atomicAdd(&cnt[colg0 + j], 1);
            if (pos < 256)
                cand[(size_t)(colg0 + j) * 256 + pos] =
                    ((unsigned long long)uu << 32) |
                    (unsigned long long)(16383 - (row0 + r));
        }
    }
}

// ---------------- kernel B: exact top-32 from candidates ----------------
__global__ __launch_bounds__(256) void topk_select(const unsigned long long* __restrict__ cand,
                                                   const int* __restrict__ cnt,
                                                   const float* __restrict__ qk,
                                                   float* __restrict__ out_idx,
                                                   float* __restrict__ out_val,
                                                   int* __restrict__ idx_sorted) {
    int bid = blockIdx.x;                // colg = b*1024 + q
    int tid = threadIdx.x;
    __shared__ unsigned long long sc[256];
    __shared__ unsigned long long selk[32];

    int C = cnt[bid];
    if (C <= 256) {
        if (tid < C) sc[tid] = cand[(size_t)bid * 256 + tid];
        __syncthreads();
        if (tid < C) {
            unsigned long long mine = sc[tid];
            int rank = 0;
            for (int j = 0; j < C; ++j) rank += (sc[j] > mine) ? 1 : 0;
            if (rank < 32) selk[rank] = mine;
        }
        __syncthreads();
    } else {
        // exact fallback: 32 rounds of strictly-descending key extraction
        int b = bid >> 10, q = bid & 1023;
        const float* colp = qk + (size_t)b * 16384 * 1024 + q;
        unsigned long long prev = ~0ull;
#pragma unroll 1
        for (int s = 0; s < 32; ++s) {
            unsigned long long best = 0;
            for (int r = tid; r < 16384; r += 256) {
                unsigned long long k =
                    ((unsigned long long)mono_u32(colp[(size_t)r * 1024]) << 32) |
                    (unsigned long long)(16383 - r);
                if (k < prev && k > best) best = k;
            }
            sc[tid] = best;
            __syncthreads();
            for (int off = 128; off >= 1; off >>= 1) {
                if (tid < off && sc[tid + off] > sc[tid]) sc[tid] = sc[tid + off];
                __syncthreads();
            }
            if (tid == 0) selk[s] = sc[0];
            __syncthreads();
            prev = selk[s];
        }
    }

    if (tid < 8) {
        unsigned long long k = selk[tid];
        unsigned uv = (unsigned)(k >> 32);
        unsigned bits = (uv & 0x80000000u) ? (uv ^ 0x80000000u) : ~uv;
        out_val[(size_t)bid * 8 + tid] = __uint_as_float(bits);
        int gi = 16383 - (int)(k & 0xFFFFFFFFull);
        out_idx[(size_t)bid * 8 + tid] = (float)gi;
    }
    if (tid < 32) {                      // 32 distinct indices -> ascending by rank
        int mine = 16383 - (int)(selk[tid] & 0xFFFFFFFFull);
        int rank = 0;
#pragma unroll
        for (int j = 0; j < 32; ++j) {
            int oj = 16383 - (int)(selk[j] & 0xFFFFFFFFull);
            rank += (oj < mine) ? 1 : 0;
        }
        idx_sorted[(size_t)bid * 32 + rank] = mine;
    }
}

// ---------------- kernel 3: blockify v2 [B,D,T,64,64] -> [B, T*1024, 4, D] ----------------
template <int D, int T>
__global__ __launch_bounds__(256) void blockify2(const float* __restrict__ in,
                                                 float* __restrict__ out) {
    constexpr int NH = D / 128;
    __shared__ float tile[128][128];     // 64KB exact; tile[c][pos ^ swz(c)]
    int wg = blockIdx.x;
    int h  = wg % NH;
    int hb = (wg / NH) % 32;
    int t  = (wg / (NH * 32)) % T;
    int b  = wg / (NH * 32 * T);
    int tid = threadIdx.x;

    // phase 1: stage 128 channels x 128 floats (row-pair), 16 staged float4 loads
    {
        int m   = tid & 31;              // float4 slot within row-pair
        int cl0 = tid >> 5;              // 0..7
        float4 v[16];
#pragma unroll
        for (int pass = 0; pass < 16; ++pass) {
            int c = pass * 8 + cl0;
            const float* src = in +
                ((size_t)(b * D + h * 128 + c) * T + t) * 4096 + (size_t)hb * 128;
            v[pass] = *(const float4*)(src + 4 * m);
        }
#pragma unroll
        for (int pass = 0; pass < 16; ++pass) {
            int c = pass * 8 + cl0;
            int sw = ((c >> 2) & 31) << 2;
            *(float4*)&tile[c][(4 * m) ^ sw] = v[pass];
        }
    }
    __syncthreads();

    // phase 2: write (wb, p, c) -> out[n][p][h*128 + c], float4 along c
    {
        size_t slab = (((size_t)b * T + t) * 1024 + (size_t)hb * 32) * (4 * D) +
                      (size_t)h * 128;
#pragma unroll
        for (int it = 0; it < 16; ++it) {
            int flat = it * 1024 + tid * 4;  // over (wb:32, p:4, c:128)
            int cl = flat & 127;             // multiple of 4
            int pp = (flat >> 7) & 3;
            int wb = flat >> 9;
            int pos = ((pp >> 1) << 6) + 2 * wb + (pp & 1);
            int sw = ((cl >> 2) & 31) << 2;  // same for cl..cl+3
            float4 o;
            o.x = tile[cl + 0][pos ^ sw];
            o.y = tile[cl + 1][pos ^ sw];
            o.z = tile[cl + 2][pos ^ sw];
            o.w = tile[cl + 3][pos ^ sw];
            *(float4*)(out + slab + (size_t)wb * 4 * D + (size_t)pp * D + cl) = o;
        }
    }
}

// ---------------- kernel 4: gathered block attention (vectorized) ----------------
// K swizzled in LDS: element (r,c) at Kbuf[r*128 + ((g ^ (r&7))<<2) + (c&3)], g=c>>2.
// b128 global gathers for K and V (1KB/wave-instr); PV: wave w owns n-quarter
// [32w,32w+32), 16 FMA per 16B loaded; cross-wave reduce through dead K buffer.
__device__ inline int kidx(int r, int g) { return r * 128 + (((g ^ (r & 7))) << 2); }

__global__ __launch_bounds__(256) void attn_kernel(const float* __restrict__ m_in_b,
                                                   const float* __restrict__ m_out_b,
                                                   const float* __restrict__ q_b,
                                                   const int* __restrict__ idx_sorted,
                                                   float* __restrict__ out) {
    int bid = blockIdx.x;
    int b = bid >> 10, qblk = bid & 1023;
    int hb = qblk >> 5, wb = qblk & 31;
    int tid = threadIdx.x;
    int w = tid >> 6, lane = tid & 63;

    __shared__ __align__(16) float Kbuf[64 * 128];   // 32KB; later reused as red[4][64][16]
    __shared__ __align__(16) float Q[4][128];
    __shared__ __align__(16) float P[4][128];
    __shared__ int blks[32];

    if (tid < 32) blks[tid] = idx_sorted[(size_t)bid * 32 + tid];
    if (tid < 128) {
        float4 qv = ((const float4*)(q_b + (size_t)bid * 512))[tid];
        *(float4*)((float*)Q + tid * 4) = qv;
    }
    __syncthreads();

    const float scale = 0.08838834764831845f;
    float s01[2];
#pragma unroll 1
    for (int half = 0; half < 2; ++half) {
        if (half) __syncthreads();
        // gather 16 blocks x 512 floats = 2048 float4, 8 per thread (b128 loads)
#pragma unroll
        for (int it = 0; it < 8; ++it) {
            int flat = it * 256 + tid;
            int ki = flat >> 7, l = flat & 127;
            const float4* src = (const float4*)(m_in_b +
                ((size_t)b * 16384 + blks[half * 16 + ki]) * 512);
            float4 v = src[l];
            int r = ki * 4 + (l >> 5);
            int g = l & 31;
            *(float4*)&Kbuf[kidx(r, g)] = v;
        }
        __syncthreads();
        float acc = 0.f;
#pragma unroll
        for (int c4 = 0; c4 < 32; ++c4) {
            float4 k4 = *(const float4*)&Kbuf[kidx(lane, c4)];
            float4 q4 = *(const float4*)&Q[w][c4 << 2];
            acc += k4.x * q4.x + k4.y * q4.y + k4.z * q4.z + k4.w * q4.w;
        }
        s01[half] = acc * scale;
    }

    float m = fmaxf(s01[0], s01[1]);
#pragma unroll
    for (int off = 32; off >= 1; off >>= 1) m = fmaxf(m, __shfl_xor(m, off, 64));
    float e0 = expf(s01[0] - m), e1 = expf(s01[1] - m);
    float sum = e0 + e1;
#pragma unroll
    for (int off = 32; off >= 1; off >>= 1) sum += __shfl_xor(sum, off, 64);
    float inv = 1.0f / sum;
    P[w][lane]      = e0 * inv;
    P[w][lane + 64] = e1 * inv;
    __syncthreads();   // scores done (K dead), P visible to all waves

    // PV: wave w handles n in [32w, 32w+32) -> blocks 8w..8w+7; thread owns
    // channels 4*lane..+3 and all 4 output pixels. a[c*4+pix].
    float a[16];
#pragma unroll
    for (int i = 0; i < 16; ++i) a[i] = 0.f;
    int c4b = lane << 2;
#pragma unroll
    for (int nq = 0; nq < 8; ++nq) {
        int n0 = (w << 5) + (nq << 2);
        float4 p0 = *(const float4*)&P[0][n0];
        float4 p1 = *(const float4*)&P[1][n0];
        float4 p2 = *(const float4*)&P[2][n0];
        float4 p3 = *(const float4*)&P[3][n0];
        const float* vbase = m_out_b +
            ((size_t)b * 16384 + blks[(w << 3) + nq]) * 1024 + c4b;
        float4 v0 = *(const float4*)(vbase);
        float4 v1 = *(const float4*)(vbase + 256);
        float4 v2 = *(const float4*)(vbase + 512);
        float4 v3 = *(const float4*)(vbase + 768);
#define ACC4(vj, px, py, pz, pw)                                          \
        a[0]  += px * vj.x; a[1]  += py * vj.x; a[2]  += pz * vj.x; a[3]  += pw * vj.x; \
        a[4]  += px * vj.y; a[5]  += py * vj.y; a[6]  += pz * vj.y; a[7]  += pw * vj.y; \
        a[8]  += px * vj.z; a[9]  += py * vj.z; a[10] += pz * vj.z; a[11] += pw * vj.z; \
        a[12] += px * vj.w; a[13] += py * vj.w; a[14] += pz * vj.w; a[15] += pw * vj.w;
        ACC4(v0, p0.x, p1.x, p2.x, p3.x)
        ACC4(v1, p0.y, p1.y, p2.y, p3.y)
        ACC4(v2, p0.z, p1.z, p2.z, p3.z)
        ACC4(v3, p0.w, p1.w, p2.w, p3.w)
#undef ACC4
    }

    // cross-wave reduction through dead Kbuf: red[w][lane][16]
    float* red = Kbuf;
    {
        int rb = (w * 64 + lane) * 16;
        *(float4*)&red[rb + 0]  = make_float4(a[0],  a[1],  a[2],  a[3]);
        *(float4*)&red[rb + 4]  = make_float4(a[4],  a[5],  a[6],  a[7]);
        *(float4*)&red[rb + 8]  = make_float4(a[8],  a[9],  a[10], a[11]);
        *(float4*)&red[rb + 12] = make_float4(a[12], a[13], a[14], a[15]);
    }
    __syncthreads();
    {
        int ch = tid;                        // 0..255
        int off = (ch >> 2) * 16 + (ch & 3) * 4;
        float4 r0 = *(const float4*)&red[0 * 1024 + off];
        float4 r1 = *(const float4*)&red[1 * 1024 + off];
        float4 r2 = *(const float4*)&red[2 * 1024 + off];
        float4 r3 = *(const float4*)&red[3 * 1024 + off];
        float o0 = r0.x + r1.x + r2.x + r3.x;
        float o1 = r0.y + r1.y + r2.y + r3.y;
        float o2 = r0.z + r1.z + r2.z + r3.z;
        float o3 = r0.w + r1.w + r2.w + r3.w;
        size_t base = (((size_t)b * 256 + ch) * 64 + hb * 2) * 64 + wb * 2;
        *(float2*)&out[base]      = make_float2(o0, o1);
        *(float2*)&out[base + 64] = make_float2(o2, o3);
    }
}

extern "C" void kernel_launch(void* const* d_in, const int* in_sizes, int n_in,
                              void* d_out, int out_size, void* d_ws, size_t ws_size,
                              hipStream_t stream) {
    const float* m_in  = (const float*)d_in[0];
    const float* m_out = (const float*)d_in[1];
    const float* q_in  = (const float*)d_in[2];
    const float* qk    = (const float*)d_in[3];

    char* ws = (char*)d_ws;
    float* m_out_b = (float*)(ws);                 // written after topk chain completes
    float* m_in_b  = (float*)(ws + 134217728);
    float* q_b     = (float*)(ws + 201326592);
    int*   idxs    = (int*)  (ws + 205520896);

    // transient top-k scratch inside the (not-yet-written) m_out_b region
    unsigned long long* cand = (unsigned long long*)(ws);        // 4MB
    float*    Mx  = (float*)   (ws + 4194304);                   // 4MB
    unsigned* t_u = (unsigned*)(ws + 8388608);                   // 8KB
    int*      cnt = (int*)     (ws + 8396800);                   // 8KB

    float* out     = (float*)d_out;
    float* out_mem = out;
    float* out_idx = out + 2097152;
    float* out_val = out + 2113536;

    qk_chunk_max<<<1024, 256, 0, stream>>>(qk, Mx);
    qk_thresh   <<<2048, 256, 0, stream>>>(Mx, t_u, cnt);
    qk_filter   <<<1024, 256, 0, stream>>>(qk, t_u, cnt, cand);
    topk_select <<<2048, 256, 0, stream>>>(cand, cnt, qk, out_idx, out_val, idxs);

    blockify2<128, 16><<<1024, 256, 0, stream>>>(m_in, m_in_b);
    blockify2<128, 1><<<64, 256, 0, stream>>>(q_in, q_b);
    blockify2<256, 16><<<2048, 256, 0, stream>>>(m_out, m_out_b);
    attn_kernel<<<2048, 256, 0, stream>>>(m_in_b, m_out_b, q_b, idxs, out_mem);
}